// Round 7
// baseline (286.847 us; speedup 1.0000x reference)
//
#include <hip/hip_runtime.h>
#include <hip/hip_bf16.h>
#include <math.h>

// Problem constants
#define B_   4
#define CIN  256
#define COUT 256
#define HW   4096   // 64*64

typedef __attribute__((ext_vector_type(8))) short short8;
typedef __attribute__((ext_vector_type(4))) float float4v;

// LDS row strides (ushorts).
// LSTR  (32-ch rows):  80 B = 20 dwords.
// LSTR2 (64-ch rows): 144 B = 36 dwords (36 mod 32 = 4 -> proven 2-way pattern).
// LSTR4 (128-ch rows): 272 B = 68 dwords (68 mod 32 = 4 -> same pattern).
#define LSTR  40
#define LSTR2 72
#define LSTR4 136

__device__ __forceinline__ float sigmoidf_(float v){ return 1.0f/(1.0f+expf(-v)); }
__device__ __forceinline__ ushort f2bf(float f){
  union { float f; unsigned u; } x; x.f = f;
  unsigned r = x.u + 0x7fffu + ((x.u>>16)&1u);
  return (ushort)(r>>16);
}
__device__ __forceinline__ float bflo(unsigned u){ union{unsigned u; float f;} c; c.u = u<<16;          return c.f; }
__device__ __forceinline__ float bfhi(unsigned u){ union{unsigned u; float f;} c; c.u = u & 0xffff0000u; return c.f; }

// ---------- transpose x [B][C][HW] -> xtb [B][HW][C] bf16 ----------
__global__ void k_transpose_x(const float* __restrict__ x, ushort* __restrict__ xtb){
  __shared__ float ts[32][33];
  int tx = threadIdx.x & 31, ty = threadIdx.x >> 5;
  int p0 = blockIdx.x * 32, c0 = blockIdx.y * 32, b = blockIdx.z;
  const float* xb = x + (size_t)b*CIN*HW;
#pragma unroll
  for(int q=0;q<4;q++){
    int c = ty + q*8;
    ts[c][tx] = xb[(size_t)(c0+c)*HW + p0+tx];
  }
  __syncthreads();
#pragma unroll
  for(int q=0;q<4;q++){
    int pr = ty + q*8;
    xtb[((size_t)(b*HW + p0+pr)<<8) + c0+tx] = f2bf(ts[tx][pr]);
  }
}

// ---------- weight re-layouts (bf16, K-chunked [kc][o][kk]) ----------
__global__ void k_build_Wob(const float* __restrict__ w_off, ushort* __restrict__ Wob){
  int f = blockIdx.x*256 + threadIdx.x;   // grid 288
  int kc = f>>10, o = (f>>5)&31, kk = f&31;
  int k = kc*32 + kk, tap = k>>8, c = k&255;
  float v = (o < 27) ? w_off[(size_t)o*2304 + c*9 + tap] : 0.f;
  Wob[f] = f2bf(v);
}
__global__ void k_build_Wdb(const float* __restrict__ w_dcn, ushort* __restrict__ Wdb){
  int f = blockIdx.x*256 + threadIdx.x;  // grid 2304
  int kc = f>>13, o = (f>>5)&255, kk = f&31;
  int k = kc>>3, c = ((kc&7)<<5) | kk;
  Wdb[f] = f2bf(w_dcn[(size_t)o*2304 + c*9 + k]);
}
__global__ void k_build_WT2c(const float* __restrict__ w_up, ushort* __restrict__ WT2c){
  int f = blockIdx.x*256 + threadIdx.x;    // grid 4096
  int pp = f>>18, kc = (f>>13)&31, o = (f>>5)&255, kk = f&31;
  int k = kc*32 + kk, ab = k>>8, c = k&255;
  int a = ab>>1, bb = ab&1, ph = pp>>1, pw = pp&1;
  WT2c[f] = f2bf(w_up[(size_t)(c*COUT+o)*16 + (3-ph-2*a)*4 + (3-pw-2*bb)]);
}

// ---------- offset conv MFMA: M=32(27), Nb=64 px, K=2304, QUAD chunks (BK=128) ----------
// 18 quad-phases. Quad q = chunks {4q..4q+3}: same tap (4q>>3==(4q+3)>>3), 128
// contiguous channels. grid (64,4), 256 thr = 4 waves. W JIT per chunk from L2.
__global__ __launch_bounds__(256) void k_offset_mfma(const ushort* __restrict__ xtb,
                        const ushort* __restrict__ Wob, float* __restrict__ om){
  __shared__ ushort Vs[2][64*LSTR4];   // 2 x 17408 B
  __shared__ int sIdx[576];
  int tid = threadIdx.x;
  int px0 = blockIdx.x * 64;
  int b   = blockIdx.y;
  for(int t=tid; t<576; t+=256){
    int tap = t>>6, px = t&63;
    int p = px0+px, hh = p>>6, ww = p&63;
    int ih = hh + tap/3 - 1, iw = ww + tap%3 - 1;
    sIdx[t] = (ih>=0 && ih<64 && iw>=0 && iw<64) ? ((b*HW + ih*64+iw)<<8) : -1;
  }
  __syncthreads();

  int lane = tid&63, wv = tid>>6, lo = lane&15, hi = lane>>4;
  float4v acc[2];
  acc[0] = acc[1] = (float4v){0.f,0.f,0.f,0.f};
  int vpx = tid>>2, vseg = tid&3;
  const int wlane = lo*32 + hi*8;   // A-frag lane offset within a chunk

// quad gather: 32 ch/thread (4x uint4), 4 thr/px cover 128 ch
#define OFF_GATHER_Q(Q, V) do{ \
    int k_ = (Q)>>1, c0_ = ((Q)&1)<<7; \
    int idx_ = sIdx[(k_<<6)+vpx]; \
    int coff_ = c0_ + (vseg<<5); \
    V[0]=make_uint4(0,0,0,0); V[1]=make_uint4(0,0,0,0); \
    V[2]=make_uint4(0,0,0,0); V[3]=make_uint4(0,0,0,0); \
    if(idx_ >= 0){ \
      V[0] = *(const uint4*)(xtb + idx_ + coff_); \
      V[1] = *(const uint4*)(xtb + idx_ + coff_ + 8); \
      V[2] = *(const uint4*)(xtb + idx_ + coff_ + 16); \
      V[3] = *(const uint4*)(xtb + idx_ + coff_ + 24); \
    } \
  }while(0)

#define OFF_VWRITE_Q(V, BUF) do{ \
    ushort* vp_ = &Vs[BUF][vpx*LSTR4 + (vseg<<5)]; \
    *(uint4*)(vp_)      = V[0]; \
    *(uint4*)(vp_ + 8)  = V[1]; \
    *(uint4*)(vp_ + 16) = V[2]; \
    *(uint4*)(vp_ + 24) = V[3]; \
  }while(0)

// compute quad Q from Vs[BUF]; W JIT per chunk (2 short8 transient)
#define OFF_COMPUTE_Q(Q, BUF) do{ \
    const ushort* bp_ = &Vs[BUF][(wv*16+lo)*LSTR4 + hi*8]; \
    _Pragma("unroll") \
    for(int c_=0;c_<4;c_++){ \
      const ushort* wp_ = Wob + (((Q)*4+c_)<<10) + wlane; \
      short8 w0_ = *(const short8*)(wp_); \
      short8 w1_ = *(const short8*)(wp_ + 512); \
      short8 ba_ = *(const short8*)(bp_ + c_*32); \
      acc[0] = __builtin_amdgcn_mfma_f32_16x16x32_bf16(w0_, ba_, acc[0], 0,0,0); \
      acc[1] = __builtin_amdgcn_mfma_f32_16x16x32_bf16(w1_, ba_, acc[1], 0,0,0); \
    } \
  }while(0)

  uint4 vE[4], vO[4];
  // ---- prologue: V quad0 -> Vs[0], V quad1 -> regs ----
  OFF_GATHER_Q(0, vE);
  OFF_VWRITE_Q(vE, 0);
  OFF_GATHER_Q(1, vO);
  __syncthreads();

#pragma unroll 1
  for(int pb=0; pb<18; pb+=2){
    { // even quad pb: compute Vs[0]; gather pb+2->E; write O->Vs[1]
      if(pb<16) OFF_GATHER_Q(pb+2, vE);
      OFF_COMPUTE_Q(pb, 0);
      OFF_VWRITE_Q(vO, 1);
      __syncthreads();
    }
    { // odd quad pb+1: compute Vs[1]; gather pb+3->O; write E->Vs[0]
      if(pb<15) OFF_GATHER_Q(pb+3, vO);
      OFF_COMPUTE_Q(pb+1, 1);
      if(pb<16) OFF_VWRITE_Q(vE, 0);
      __syncthreads();
    }
  }
  int p = px0 + wv*16 + lo;
#pragma unroll
  for(int mi=0;mi<2;mi++){
    int ob = mi*16 + hi*4;
    float4v a = (mi==0) ? acc[0] : acc[1];
#pragma unroll
    for(int r=0;r<4;r++){
      int o = ob + r;
      if(o < 27) om[(size_t)(b*27+o)*HW + p] = a[r];
    }
  }
}

// ---------- DCN MFMA: Mb=256, Nb=64, K=2304, QUAD chunks (BK=128) ----------
// 18 quad-phases. grid (64,4), 512 thr = 8 waves (2/SIMD).
// Quad shares tap -> one sPk/sCf lookup; 4 corners x 32B gathers (8 loads/thr);
// two b128 blend-writes per thread per phase. W JIT per chunk from L2 (no W dbuf).
// b_dcn dropped: BN1 subtracts the per-channel mean, so a uniform bias cancels.
#define DCN_GATHER_Q(Q, C, CF) do{ \
    int k_ = (Q)>>1, c0_ = ((Q)&1)<<7; \
    int t_ = (k_<<6) + vpx; \
    int pk_ = sPk[t_]; CF = sCf[t_]; \
    int coff_ = c0_ + (vseg<<4); \
    int iy0_=pk_&63, iy1_=(pk_>>6)&63, ix0_=(pk_>>12)&63, ix1_=(pk_>>18)&63; \
    const ushort* p00_ = xtb + cbase + (((iy0_<<6)+ix0_)<<8) + coff_; \
    const ushort* p01_ = xtb + cbase + (((iy0_<<6)+ix1_)<<8) + coff_; \
    const ushort* p10_ = xtb + cbase + (((iy1_<<6)+ix0_)<<8) + coff_; \
    const ushort* p11_ = xtb + cbase + (((iy1_<<6)+ix1_)<<8) + coff_; \
    C[0] = *(const uint4*)(p00_);     C[4] = *(const uint4*)(p00_ + 8); \
    C[1] = *(const uint4*)(p01_);     C[5] = *(const uint4*)(p01_ + 8); \
    C[2] = *(const uint4*)(p10_);     C[6] = *(const uint4*)(p10_ + 8); \
    C[3] = *(const uint4*)(p11_);     C[7] = *(const uint4*)(p11_ + 8); \
  }while(0)

#define DCN_BLEND_H(C0,C1,C2,C3, CF, DST) do{ \
    union{ ushort us[8]; uint4 q; } rr_; \
    rr_.us[0] = f2bf(CF.x*bflo(C0.x)+CF.y*bflo(C1.x)+CF.z*bflo(C2.x)+CF.w*bflo(C3.x)); \
    rr_.us[1] = f2bf(CF.x*bfhi(C0.x)+CF.y*bfhi(C1.x)+CF.z*bfhi(C2.x)+CF.w*bfhi(C3.x)); \
    rr_.us[2] = f2bf(CF.x*bflo(C0.y)+CF.y*bflo(C1.y)+CF.z*bflo(C2.y)+CF.w*bflo(C3.y)); \
    rr_.us[3] = f2bf(CF.x*bfhi(C0.y)+CF.y*bfhi(C1.y)+CF.z*bfhi(C2.y)+CF.w*bfhi(C3.y)); \
    rr_.us[4] = f2bf(CF.x*bflo(C0.z)+CF.y*bflo(C1.z)+CF.z*bflo(C2.z)+CF.w*bflo(C3.z)); \
    rr_.us[5] = f2bf(CF.x*bfhi(C0.z)+CF.y*bfhi(C1.z)+CF.z*bfhi(C2.z)+CF.w*bfhi(C3.z)); \
    rr_.us[6] = f2bf(CF.x*bflo(C0.w)+CF.y*bflo(C1.w)+CF.z*bflo(C2.w)+CF.w*bflo(C3.w)); \
    rr_.us[7] = f2bf(CF.x*bfhi(C0.w)+CF.y*bfhi(C1.w)+CF.z*bfhi(C2.w)+CF.w*bfhi(C3.w)); \
    *(uint4*)(DST) = rr_.q; \
  }while(0)

#define DCN_BLEND_Q(C, CF, BUF) do{ \
    ushort* dp_ = &Vs[BUF][vpx*LSTR4 + (vseg<<4)]; \
    DCN_BLEND_H(C[0],C[1],C[2],C[3], CF, dp_); \
    DCN_BLEND_H(C[4],C[5],C[6],C[7], CF, dp_ + 8); \
  }while(0)

// compute quad Q from Vs[BUF]; W JIT per chunk (4 short8 transient)
#define DCN_COMPUTE_Q(Q, BUF) do{ \
    const ushort* bp_ = &Vs[BUF][(pn0+lo)*LSTR4 + hi*8]; \
    _Pragma("unroll") \
    for(int c_=0;c_<4;c_++){ \
      const ushort* wp_ = Wdb + ((size_t)((Q)*4+c_)<<13) + wlane; \
      short8 w0_ = *(const short8*)(wp_); \
      short8 w1_ = *(const short8*)(wp_ + 512); \
      short8 w2_ = *(const short8*)(wp_ + 1024); \
      short8 w3_ = *(const short8*)(wp_ + 1536); \
      short8 b0_ = *(const short8*)(bp_ + c_*32); \
      short8 b1_ = *(const short8*)(bp_ + c_*32 + 16*LSTR4); \
      acc[0][0] = __builtin_amdgcn_mfma_f32_16x16x32_bf16(w0_, b0_, acc[0][0], 0,0,0); \
      acc[0][1] = __builtin_amdgcn_mfma_f32_16x16x32_bf16(w0_, b1_, acc[0][1], 0,0,0); \
      acc[1][0] = __builtin_amdgcn_mfma_f32_16x16x32_bf16(w1_, b0_, acc[1][0], 0,0,0); \
      acc[1][1] = __builtin_amdgcn_mfma_f32_16x16x32_bf16(w1_, b1_, acc[1][1], 0,0,0); \
      acc[2][0] = __builtin_amdgcn_mfma_f32_16x16x32_bf16(w2_, b0_, acc[2][0], 0,0,0); \
      acc[2][1] = __builtin_amdgcn_mfma_f32_16x16x32_bf16(w2_, b1_, acc[2][1], 0,0,0); \
      acc[3][0] = __builtin_amdgcn_mfma_f32_16x16x32_bf16(w3_, b0_, acc[3][0], 0,0,0); \
      acc[3][1] = __builtin_amdgcn_mfma_f32_16x16x32_bf16(w3_, b1_, acc[3][1], 0,0,0); \
    } \
  }while(0)

__global__ __launch_bounds__(512) void k_dcn_mfma(const ushort* __restrict__ xtb,
                        const float* __restrict__ om, const float* __restrict__ b_off,
                        const ushort* __restrict__ Wdb, float* __restrict__ out1){
  __shared__ ushort Vs[2][64*LSTR4];   // 2 x 17408 B
  __shared__ int    sPk[576];
  __shared__ float4 sCf[576];
  int tid = threadIdx.x;
  int px0 = blockIdx.x * 64;
  int b   = blockIdx.y;

  for(int t=tid; t<576; t+=512){
    int k = t>>6, px = t&63;
    int p = px0 + px, hh = p>>6, ww = p&63;
    const float* omp = om + (size_t)b*27*HW + p;
    float dy = omp[(size_t)k*HW]      + b_off[k];
    float dx = omp[(size_t)(9+k)*HW]  + b_off[9+k];
    float mo = sigmoidf_(omp[(size_t)(18+k)*HW] + b_off[18+k]);
    float py  = dy + (float)(hh + k/3 - 1);
    float pxf = dx + (float)(ww + k%3 - 1);
    float y0 = floorf(py), x0 = floorf(pxf);
    float wy = py - y0, wx = pxf - x0;
    float y1 = y0 + 1.0f, x1 = x0 + 1.0f;
    bool vy0 = (y0>=0.f)&&(y0<=63.f), vy1 = (y1>=0.f)&&(y1<=63.f);
    bool vx0 = (x0>=0.f)&&(x0<=63.f), vx1 = (x1>=0.f)&&(x1<=63.f);
    int iy0 = (int)fminf(fmaxf(y0,0.f),63.f);
    int iy1 = (int)fminf(fmaxf(y1,0.f),63.f);
    int ix0 = (int)fminf(fmaxf(x0,0.f),63.f);
    int ix1 = (int)fminf(fmaxf(x1,0.f),63.f);
    sPk[t] = iy0 | (iy1<<6) | (ix0<<12) | (ix1<<18);
    sCf[t] = make_float4((vy0&&vx0)? (1.f-wy)*(1.f-wx)*mo : 0.f,
                         (vy0&&vx1)? (1.f-wy)*wx*mo       : 0.f,
                         (vy1&&vx0)? wy*(1.f-wx)*mo       : 0.f,
                         (vy1&&vx1)? wy*wx*mo             : 0.f);
  }
  __syncthreads();

  int lane = tid&63, wv = tid>>6, lo = lane&15, hi = lane>>4;
  int om0 = (wv>>1)*64, pn0 = (wv&1)*32;
  float4v acc[4][2];
#pragma unroll
  for(int i=0;i<4;i++)
#pragma unroll
    for(int j=0;j<2;j++) acc[i][j] = (float4v){0.f,0.f,0.f,0.f};
  int cbase = (b*HW)<<8;
  int vpx = tid>>3, vseg = tid&7;
  const int wlane = (om0+lo)*32 + hi*8;   // A-frag lane offset within a chunk

  uint4 cE[8], cO[8];
  float4 fE, fO;

  // ---- prologue: gather+blend quad0 -> Vs[0], gather quad1 -> O ----
  DCN_GATHER_Q(0, cE, fE);
  DCN_BLEND_Q(cE, fE, 0);
  DCN_GATHER_Q(1, cO, fO);
  __syncthreads();

#pragma unroll 1
  for(int pb=0; pb<18; pb+=2){
    { // even quad pb: compute Vs[0]; gather pb+2->E; blend O->Vs[1]
      if(pb<16) DCN_GATHER_Q(pb+2, cE, fE);
      DCN_COMPUTE_Q(pb, 0);
      DCN_BLEND_Q(cO, fO, 1);
      __syncthreads();
    }
    { // odd quad pb+1: compute Vs[1]; gather pb+3->O; blend E->Vs[0]
      if(pb<15) DCN_GATHER_Q(pb+3, cO, fO);
      DCN_COMPUTE_Q(pb+1, 1);
      if(pb<16) DCN_BLEND_Q(cE, fE, 0);
      __syncthreads();
    }
  }

#pragma unroll
  for(int i=0;i<4;i++){
    int ob = om0 + i*16 + hi*4;
#pragma unroll
    for(int r=0;r<4;r++){
      int o = ob + r;
      float* op = out1 + (size_t)(b*COUT + o)*HW + px0 + pn0 + lo;
#pragma unroll
      for(int j=0;j<2;j++) op[j*16] = acc[i][j][r];
    }
  }
}

// ---------- batchnorm stats (f32 input, for out1) ----------
__global__ void k_bn_stats(const float* __restrict__ xin, float* __restrict__ stats, int per_b){
  int o = blockIdx.x, tid = threadIdx.x;
  float s=0.f, ss=0.f;
  for(int b=0;b<B_;b++){
    const float* p = xin + (size_t)(b*COUT+o)*per_b;
    for(int i=tid;i<per_b;i+=256){ float v = p[i]; s+=v; ss+=v*v; }
  }
  __shared__ float rs[256], rss[256];
  rs[tid]=s; rss[tid]=ss; __syncthreads();
  for(int st=128; st>0; st>>=1){
    if(tid<st){ rs[tid]+=rs[tid+st]; rss[tid]+=rss[tid+st]; }
    __syncthreads();
  }
  if(tid==0){
    float n = (float)(B_*per_b);
    float mean = rs[0]/n;
    float var  = rss[0]/n - mean*mean;
    stats[o*2] = mean; stats[o*2+1] = rsqrtf(var + 1e-5f);
  }
}

// ---------- batchnorm stats over bf16 ct [16 planes][o][4096] ----------
__global__ void k_bn_stats_ct(const ushort* __restrict__ ct, float* __restrict__ stats){
  int o = blockIdx.x, tid = threadIdx.x;
  float s=0.f, ss=0.f;
  for(int pl=0; pl<16; ++pl){
    const ushort* p = ct + (((size_t)(pl*256 + o))<<12);
    for(int i=tid*8; i<4096; i+=2048){
      uint4 v = *(const uint4*)(p + i);
      float f;
      f=bflo(v.x); s+=f; ss+=f*f;  f=bfhi(v.x); s+=f; ss+=f*f;
      f=bflo(v.y); s+=f; ss+=f*f;  f=bfhi(v.y); s+=f; ss+=f*f;
      f=bflo(v.z); s+=f; ss+=f*f;  f=bfhi(v.z); s+=f; ss+=f*f;
      f=bflo(v.w); s+=f; ss+=f*f;  f=bfhi(v.w); s+=f; ss+=f*f;
    }
  }
  __shared__ float rs[256], rss[256];
  rs[tid]=s; rss[tid]=ss; __syncthreads();
  for(int st=128; st>0; st>>=1){
    if(tid<st){ rs[tid]+=rs[tid+st]; rss[tid]+=rss[tid+st]; }
    __syncthreads();
  }
  if(tid==0){
    float n = (float)(16*4096);
    float mean = rs[0]/n;
    float var  = rss[0]/n - mean*mean;
    stats[o*2] = mean; stats[o*2+1] = rsqrtf(var + 1e-5f);
  }
}

// ---------- BN1 apply + relu + transpose -> y1b bf16 [b][p][c] ----------
__global__ void k_bn1_apply_t(const float* __restrict__ out1, const float* __restrict__ stats,
                              const float* __restrict__ gamma, const float* __restrict__ beta,
                              ushort* __restrict__ y1b){
  __shared__ float ts[32][33];
  int tx = threadIdx.x & 31, ty = threadIdx.x >> 5;
  int p0 = blockIdx.x*32, o0 = blockIdx.y*32, b = blockIdx.z;
#pragma unroll
  for(int q=0;q<4;q++){
    int oo = ty + q*8; int o = o0 + oo;
    float m = stats[o*2], rstd = stats[o*2+1];
    float scale = rstd * gamma[o];
    float shift = beta[o] - m * scale;
    float v = out1[(size_t)(b*COUT+o)*HW + p0+tx];
    ts[oo][tx] = fmaxf(v*scale + shift, 0.f);
  }
  __syncthreads();
#pragma unroll
  for(int q=0;q<4;q++){
    int pr = ty + q*8;
    y1b[((size_t)(b*HW + p0+pr)<<8) + o0+tx] = f2bf(ts[tx][pr]);
  }
}

// ---------- conv-transpose MFMA v3: Mb=256 o, Nb=256 px, one (b,pp) ----------
// grid (16,4,4) = 256 blocks, 512 thr = 8 waves (2/SIMD).
// 16 PAIRED phases (BK=64). W JIT from L2 per half-phase. Vs-only dbuf LDS.
__global__ __launch_bounds__(512) void k_convt_mfma(const ushort* __restrict__ y1b,
                        const ushort* __restrict__ WT2c,
                        ushort* __restrict__ ct){
  __shared__ ushort Vs[2][256*LSTR2];   // 2 x 36864 B
  __shared__ int sIdx[1024];
  int tid = threadIdx.x;
  int px0 = blockIdx.x * 256;
  int b   = blockIdx.y;
  int pp  = blockIdx.z;
  int ph = pp>>1, pw = pp&1;

  for(int t=tid; t<1024; t+=512){
    int ab = t>>8, px = t&255;
    int a = ab>>1, bb = ab&1;
    int p = px0+px, r = p>>6, s = p&63;
    int ih = r + ph - 1 + a, iw = s + pw - 1 + bb;
    sIdx[t] = (ih>=0 && ih<64 && iw>=0 && iw<64) ? ((b*HW + ih*64+iw)<<8) : -1;
  }
  __syncthreads();

  int lane = tid&63, wv = tid>>6, lo = lane&15, hi = lane>>4;
  int om0 = (wv>>1)*64;
  int pn0 = (wv&1)*128;
  float4v acc[4][8];
#pragma unroll
  for(int i=0;i<4;i++)
#pragma unroll
    for(int j=0;j<8;j++) acc[i][j] = (float4v){0.f,0.f,0.f,0.f};

  const ushort* wbase = WT2c + ((size_t)pp<<18);
  const int wlaneb = (om0+lo)*32 + hi*8;  // A-frag lane offset within a chunk
  int vpx = tid>>1, vseg = tid&1;         // 2 thr/px, 32 ch each
  uint4 vpre[4];

// pair pc = chunks {2pc,2pc+1}: same ab tap (pc>>2), channels (pc&3)*64..+64.
#define CT3_PREFETCH(PC) do{ \
    int kc0_ = (PC)*2; \
    int ab_ = kc0_>>3, c0_ = (kc0_&7)<<5; \
    int idx_ = sIdx[(ab_<<8) + vpx]; \
    int co_ = c0_ + vseg*32; \
    vpre[0]=make_uint4(0,0,0,0); vpre[1]=make_uint4(0,0,0,0); \
    vpre[2]=make_uint4(0,0,0,0); vpre[3]=make_uint4(0,0,0,0); \
    if(idx_ >= 0){ \
      vpre[0] = *(const uint4*)(y1b + idx_ + co_); \
      vpre[1] = *(const uint4*)(y1b + idx_ + co_ + 8); \
      vpre[2] = *(const uint4*)(y1b + idx_ + co_ + 16); \
      vpre[3] = *(const uint4*)(y1b + idx_ + co_ + 24); \
    } \
  }while(0)

#define CT3_WRITE(BUF) do{ \
    ushort* vp_ = &Vs[BUF][vpx*LSTR2 + vseg*32]; \
    *(uint4*)(vp_)      = vpre[0]; \
    *(uint4*)(vp_ + 8)  = vpre[1]; \
    *(uint4*)(vp_ + 16) = vpre[2]; \
    *(uint4*)(vp_ + 24) = vpre[3]; \
  }while(0)

  // ---- prologue: pair0 -> buf0 ----
  CT3_PREFETCH(0);
  CT3_WRITE(0);
  __syncthreads();

#pragma unroll 1
  for(int pc=0; pc<16; ++pc){
    int cur = pc&1;
    if(pc < 15) CT3_PREFETCH(pc+1);
#pragma unroll
    for(int c=0; c<2; ++c){
      const ushort* wp = wbase + ((size_t)(((pc<<1)|c))<<13) + wlaneb;
      const ushort* bp = &Vs[cur][(pn0+lo)*LSTR2 + c*32 + hi*8];
      short8 bfr[8];
#pragma unroll
      for(int j=0;j<8;j++) bfr[j] = *(const short8*)(bp + j*16*LSTR2);
#pragma unroll
      for(int i=0;i<4;i++){
        short8 afr = *(const short8*)(wp + i*512);
#pragma unroll
        for(int j=0;j<8;j++)
          acc[i][j] = __builtin_amdgcn_mfma_f32_16x16x32_bf16(afr, bfr[j], acc[i][j], 0,0,0);
      }
    }
    if(pc < 15) CT3_WRITE(cur^1);
    __syncthreads();
  }

  ushort* cb = ct + (((size_t)(pp*4 + b)*256)<<12);
#pragma unroll
  for(int i=0;i<4;i++){
#pragma unroll
    for(int r=0;r<4;r++){
      int o = om0 + i*16 + hi*4 + r;
      ushort* row = cb + ((size_t)o<<12) + px0 + pn0 + lo;
#pragma unroll
      for(int j=0;j<8;j++) row[j*16] = f2bf(acc[i][j][r]);
    }
  }
}

// ---------- BN2 apply + relu + parity interleave: ct bf16 -> out f32 ----------
__global__ void k_bn2_apply(const ushort* __restrict__ ct, const float* __restrict__ stats,
                            const float* __restrict__ gamma, const float* __restrict__ beta,
                            float* __restrict__ out){
  int gid = blockIdx.x*256 + threadIdx.x;   // grid 16384
  int e4 = gid<<2;
  int b = e4>>22, o = (e4>>14)&255, q = e4&16383;
  int H2 = q>>7, W2 = q&127;
  int r = H2>>1, ph = H2&1, s0 = W2>>1;
  size_t base0 = (((size_t)((ph*2)*4 + b)*256 + o)<<12) + r*64 + s0;
  unsigned u0 = *(const unsigned*)(ct + base0);
  unsigned u1 = *(const unsigned*)(ct + base0 + ((size_t)4<<20));
  float m = stats[o*2], rstd = stats[o*2+1];
  float sc = rstd * gamma[o];
  float sh = beta[o] - m * sc;
  float4 v;
  v.x = fmaxf(bflo(u0)*sc + sh, 0.f);
  v.y = fmaxf(bflo(u1)*sc + sh, 0.f);
  v.z = fmaxf(bfhi(u0)*sc + sh, 0.f);
  v.w = fmaxf(bfhi(u1)*sc + sh, 0.f);
  *(float4*)(out + e4) = v;
}

extern "C" void kernel_launch(void* const* d_in, const int* in_sizes, int n_in,
                              void* d_out, int out_size, void* d_ws, size_t ws_size,
                              hipStream_t stream){
  (void)in_sizes; (void)n_in; (void)out_size; (void)ws_size;
  const float* x     = (const float*)d_in[0];
  const float* w_off = (const float*)d_in[1];
  const float* b_off = (const float*)d_in[2];
  const float* w_dcn = (const float*)d_in[3];
  const float* gamma1= (const float*)d_in[5];
  const float* beta1 = (const float*)d_in[6];
  const float* w_up  = (const float*)d_in[7];
  const float* gamma2= (const float*)d_in[8];
  const float* beta2 = (const float*)d_in[9];
  float* out = (float*)d_out;

  // Workspace (floats). ct (bf16, 32 MB = 8388608 floats) aliases om+xtb+out1,
  // all of which are dead before k_convt_mfma runs.
  float* ws   = (float*)d_ws;
  ushort* ct  = (ushort*)ws;                       // [0, 8388608) floats
  float* om   = ws;                                // 442368 floats
  ushort* xtb = (ushort*)(ws + 442368);            // 4194304 bf16 = 2097152 floats
  float* out1 = ws + 442368 + 2097152;             // 4194304 floats, ends 6733824 < 8388608
  float* base2 = ws + 8388608;
  ushort* y1b  = (ushort*)base2;                                   // 4194304 bf16
  ushort* WT2c = (ushort*)(base2 + 2097152);                       // 1048576 bf16
  ushort* Wdb  = (ushort*)(base2 + 2097152 + 524288);              // 589824 bf16
  ushort* Wob  = (ushort*)(base2 + 2097152 + 524288 + 294912);     // 73728 bf16
  float* st1   = base2 + 2097152 + 524288 + 294912 + 36864;        // 512
  float* st2   = st1 + 512;                                        // 512

  k_transpose_x <<<dim3(128,8,4), 256, 0, stream>>>(x, xtb);
  k_build_Wob   <<<288,  256, 0, stream>>>(w_off, Wob);
  k_build_Wdb   <<<2304, 256, 0, stream>>>(w_dcn, Wdb);
  k_build_WT2c  <<<4096, 256, 0, stream>>>(w_up, WT2c);
  k_offset_mfma <<<dim3(64,4),  256, 0, stream>>>(xtb, Wob, om);
  k_dcn_mfma    <<<dim3(64,4),  512, 0, stream>>>(xtb, om, b_off, Wdb, out1);
  k_bn_stats    <<<256,  256, 0, stream>>>(out1, st1, 4096);
  k_bn1_apply_t <<<dim3(128,8,4), 256, 0, stream>>>(out1, st1, gamma1, beta1, y1b);
  k_convt_mfma  <<<dim3(16,4,4),  512, 0, stream>>>(y1b, WT2c, ct);
  k_bn_stats_ct <<<256,  256, 0, stream>>>(ct, st2);
  k_bn2_apply   <<<16384,256, 0, stream>>>(ct, st2, gamma2, beta2, out);
}

// Round 8
// 274.755 us; speedup vs baseline: 1.0440x; 1.0440x over previous
//
#include <hip/hip_runtime.h>
#include <hip/hip_bf16.h>
#include <math.h>

// Problem constants
#define B_   4
#define CIN  256
#define COUT 256
#define HW   4096   // 64*64

typedef __attribute__((ext_vector_type(8))) short short8;
typedef __attribute__((ext_vector_type(4))) float float4v;

// LDS row strides (ushorts).
// LSTR2 (64-ch rows): 144 B = 36 dwords (36 mod 32 = 4 -> proven 2-way pattern).
// LSTR4 (128-ch rows): 272 B = 68 dwords (68 mod 32 = 4 -> same pattern).
#define LSTR  40
#define LSTR2 72
#define LSTR4 136

__device__ __forceinline__ float sigmoidf_(float v){ return 1.0f/(1.0f+expf(-v)); }
__device__ __forceinline__ ushort f2bf(float f){
  union { float f; unsigned u; } x; x.f = f;
  unsigned r = x.u + 0x7fffu + ((x.u>>16)&1u);
  return (ushort)(r>>16);
}
__device__ __forceinline__ float bflo(unsigned u){ union{unsigned u; float f;} c; c.u = u<<16;          return c.f; }
__device__ __forceinline__ float bfhi(unsigned u){ union{unsigned u; float f;} c; c.u = u & 0xffff0000u; return c.f; }

// ---------- transpose x [B][C][HW] -> xtb [B][HW][C] bf16 ----------
__global__ void k_transpose_x(const float* __restrict__ x, ushort* __restrict__ xtb){
  __shared__ float ts[32][33];
  int tx = threadIdx.x & 31, ty = threadIdx.x >> 5;
  int p0 = blockIdx.x * 32, c0 = blockIdx.y * 32, b = blockIdx.z;
  const float* xb = x + (size_t)b*CIN*HW;
#pragma unroll
  for(int q=0;q<4;q++){
    int c = ty + q*8;
    ts[c][tx] = xb[(size_t)(c0+c)*HW + p0+tx];
  }
  __syncthreads();
#pragma unroll
  for(int q=0;q<4;q++){
    int pr = ty + q*8;
    xtb[((size_t)(b*HW + p0+pr)<<8) + c0+tx] = f2bf(ts[tx][pr]);
  }
}

// ---------- weight re-layouts (bf16, K-chunked [kc][o][kk]) ----------
__global__ void k_build_Wob(const float* __restrict__ w_off, ushort* __restrict__ Wob){
  int f = blockIdx.x*256 + threadIdx.x;   // grid 288
  int kc = f>>10, o = (f>>5)&31, kk = f&31;
  int k = kc*32 + kk, tap = k>>8, c = k&255;
  float v = (o < 27) ? w_off[(size_t)o*2304 + c*9 + tap] : 0.f;
  Wob[f] = f2bf(v);
}
__global__ void k_build_Wdb(const float* __restrict__ w_dcn, ushort* __restrict__ Wdb){
  int f = blockIdx.x*256 + threadIdx.x;  // grid 2304
  int kc = f>>13, o = (f>>5)&255, kk = f&31;
  int k = kc>>3, c = ((kc&7)<<5) | kk;
  Wdb[f] = f2bf(w_dcn[(size_t)o*2304 + c*9 + k]);
}
__global__ void k_build_WT2c(const float* __restrict__ w_up, ushort* __restrict__ WT2c){
  int f = blockIdx.x*256 + threadIdx.x;    // grid 4096
  int pp = f>>18, kc = (f>>13)&31, o = (f>>5)&255, kk = f&31;
  int k = kc*32 + kk, ab = k>>8, c = k&255;
  int a = ab>>1, bb = ab&1, ph = pp>>1, pw = pp&1;
  WT2c[f] = f2bf(w_up[(size_t)(c*COUT+o)*16 + (3-ph-2*a)*4 + (3-pw-2*bb)]);
}

// ---------- offset conv MFMA: M=32(27), Nb=64 px, K=2304, QUAD chunks (BK=128) ----------
// 18 quad-phases. Per phase: ALL 8 W loads issued FIRST (vmcnt-oldest, latency
// hides under gathers+ds_reads), then gathers (stay in flight through compute).
__global__ __launch_bounds__(256) void k_offset_mfma(const ushort* __restrict__ xtb,
                        const ushort* __restrict__ Wob, float* __restrict__ om){
  __shared__ ushort Vs[2][64*LSTR4];   // 2 x 17408 B
  __shared__ int sIdx[576];
  int tid = threadIdx.x;
  int px0 = blockIdx.x * 64;
  int b   = blockIdx.y;
  for(int t=tid; t<576; t+=256){
    int tap = t>>6, px = t&63;
    int p = px0+px, hh = p>>6, ww = p&63;
    int ih = hh + tap/3 - 1, iw = ww + tap%3 - 1;
    sIdx[t] = (ih>=0 && ih<64 && iw>=0 && iw<64) ? ((b*HW + ih*64+iw)<<8) : -1;
  }
  __syncthreads();

  int lane = tid&63, wv = tid>>6, lo = lane&15, hi = lane>>4;
  float4v acc[2];
  acc[0] = acc[1] = (float4v){0.f,0.f,0.f,0.f};
  int vpx = tid>>2, vseg = tid&3;
  const int wlane = lo*32 + hi*8;   // A-frag lane offset within a chunk

// issue all 8 W fragments for quad Q (4 chunks x 2 m-tiles)
#define OFF_WLOAD_ALLQ(Q, W) do{ \
    _Pragma("unroll") \
    for(int c_=0;c_<4;c_++){ \
      const ushort* wp_ = Wob + (((Q)*4+c_)<<10) + wlane; \
      W[2*c_+0] = *(const short8*)(wp_); \
      W[2*c_+1] = *(const short8*)(wp_ + 512); \
    } \
  }while(0)

// quad gather: 32 ch/thread (4x uint4), 4 thr/px cover 128 ch
#define OFF_GATHER_Q(Q, V) do{ \
    int k_ = (Q)>>1, c0_ = ((Q)&1)<<7; \
    int idx_ = sIdx[(k_<<6)+vpx]; \
    int coff_ = c0_ + (vseg<<5); \
    V[0]=make_uint4(0,0,0,0); V[1]=make_uint4(0,0,0,0); \
    V[2]=make_uint4(0,0,0,0); V[3]=make_uint4(0,0,0,0); \
    if(idx_ >= 0){ \
      V[0] = *(const uint4*)(xtb + idx_ + coff_); \
      V[1] = *(const uint4*)(xtb + idx_ + coff_ + 8); \
      V[2] = *(const uint4*)(xtb + idx_ + coff_ + 16); \
      V[3] = *(const uint4*)(xtb + idx_ + coff_ + 24); \
    } \
  }while(0)

#define OFF_VWRITE_Q(V, BUF) do{ \
    ushort* vp_ = &Vs[BUF][vpx*LSTR4 + (vseg<<5)]; \
    *(uint4*)(vp_)      = V[0]; \
    *(uint4*)(vp_ + 8)  = V[1]; \
    *(uint4*)(vp_ + 16) = V[2]; \
    *(uint4*)(vp_ + 24) = V[3]; \
  }while(0)

#define OFF_COMPUTE_Q2(W, BUF) do{ \
    const ushort* bp_ = &Vs[BUF][(wv*16+lo)*LSTR4 + hi*8]; \
    _Pragma("unroll") \
    for(int c_=0;c_<4;c_++){ \
      short8 ba_ = *(const short8*)(bp_ + c_*32); \
      acc[0] = __builtin_amdgcn_mfma_f32_16x16x32_bf16(W[2*c_+0], ba_, acc[0], 0,0,0); \
      acc[1] = __builtin_amdgcn_mfma_f32_16x16x32_bf16(W[2*c_+1], ba_, acc[1], 0,0,0); \
    } \
  }while(0)

  short8 w[8];
  uint4 vE[4], vO[4];
  // ---- prologue: V quad0 -> Vs[0], V quad1 -> regs ----
  OFF_GATHER_Q(0, vE);
  OFF_VWRITE_Q(vE, 0);
  OFF_GATHER_Q(1, vO);
  __syncthreads();

#pragma unroll 1
  for(int pb=0; pb<18; pb+=2){
    { // even quad pb: W(pb) first; gather pb+2->E; compute Vs[0]; write O->Vs[1]
      OFF_WLOAD_ALLQ(pb, w);
      if(pb<16) OFF_GATHER_Q(pb+2, vE);
      OFF_COMPUTE_Q2(w, 0);
      OFF_VWRITE_Q(vO, 1);
      __syncthreads();
    }
    { // odd quad pb+1: W(pb+1) first; gather pb+3->O; compute Vs[1]; write E->Vs[0]
      OFF_WLOAD_ALLQ(pb+1, w);
      if(pb<15) OFF_GATHER_Q(pb+3, vO);
      OFF_COMPUTE_Q2(w, 1);
      if(pb<16) OFF_VWRITE_Q(vE, 0);
      __syncthreads();
    }
  }
  int p = px0 + wv*16 + lo;
#pragma unroll
  for(int mi=0;mi<2;mi++){
    int ob = mi*16 + hi*4;
    float4v a = (mi==0) ? acc[0] : acc[1];
#pragma unroll
    for(int r=0;r<4;r++){
      int o = ob + r;
      if(o < 27) om[(size_t)(b*27+o)*HW + p] = a[r];
    }
  }
}

// ---------- DCN MFMA: Mb=256, Nb=64, K=2304, QUAD chunks (BK=128) ----------
// 18 quad-phases. grid (64,4), 512 thr = 8 waves (2/SIMD).
// Per phase: ALL 16 W loads issued FIRST, then gathers; compute's counted vmcnt
// waits only for W (oldest), gathers stay in flight until the blend.
// b_dcn dropped: BN1 subtracts the per-channel mean, so a uniform bias cancels.
#define DCN_WLOAD_ALLQ(Q, W) do{ \
    _Pragma("unroll") \
    for(int c_=0;c_<4;c_++){ \
      const ushort* wp_ = Wdb + ((size_t)((Q)*4+c_)<<13) + wlane; \
      W[4*c_+0] = *(const short8*)(wp_); \
      W[4*c_+1] = *(const short8*)(wp_ + 512); \
      W[4*c_+2] = *(const short8*)(wp_ + 1024); \
      W[4*c_+3] = *(const short8*)(wp_ + 1536); \
    } \
  }while(0)

#define DCN_GATHER_Q(Q, C, CF) do{ \
    int k_ = (Q)>>1, c0_ = ((Q)&1)<<7; \
    int t_ = (k_<<6) + vpx; \
    int pk_ = sPk[t_]; CF = sCf[t_]; \
    int coff_ = c0_ + (vseg<<4); \
    int iy0_=pk_&63, iy1_=(pk_>>6)&63, ix0_=(pk_>>12)&63, ix1_=(pk_>>18)&63; \
    const ushort* p00_ = xtb + cbase + (((iy0_<<6)+ix0_)<<8) + coff_; \
    const ushort* p01_ = xtb + cbase + (((iy0_<<6)+ix1_)<<8) + coff_; \
    const ushort* p10_ = xtb + cbase + (((iy1_<<6)+ix0_)<<8) + coff_; \
    const ushort* p11_ = xtb + cbase + (((iy1_<<6)+ix1_)<<8) + coff_; \
    C[0] = *(const uint4*)(p00_);     C[4] = *(const uint4*)(p00_ + 8); \
    C[1] = *(const uint4*)(p01_);     C[5] = *(const uint4*)(p01_ + 8); \
    C[2] = *(const uint4*)(p10_);     C[6] = *(const uint4*)(p10_ + 8); \
    C[3] = *(const uint4*)(p11_);     C[7] = *(const uint4*)(p11_ + 8); \
  }while(0)

#define DCN_BLEND_H(C0,C1,C2,C3, CF, DST) do{ \
    union{ ushort us[8]; uint4 q; } rr_; \
    rr_.us[0] = f2bf(CF.x*bflo(C0.x)+CF.y*bflo(C1.x)+CF.z*bflo(C2.x)+CF.w*bflo(C3.x)); \
    rr_.us[1] = f2bf(CF.x*bfhi(C0.x)+CF.y*bfhi(C1.x)+CF.z*bfhi(C2.x)+CF.w*bfhi(C3.x)); \
    rr_.us[2] = f2bf(CF.x*bflo(C0.y)+CF.y*bflo(C1.y)+CF.z*bflo(C2.y)+CF.w*bflo(C3.y)); \
    rr_.us[3] = f2bf(CF.x*bfhi(C0.y)+CF.y*bfhi(C1.y)+CF.z*bfhi(C2.y)+CF.w*bfhi(C3.y)); \
    rr_.us[4] = f2bf(CF.x*bflo(C0.z)+CF.y*bflo(C1.z)+CF.z*bflo(C2.z)+CF.w*bflo(C3.z)); \
    rr_.us[5] = f2bf(CF.x*bfhi(C0.z)+CF.y*bfhi(C1.z)+CF.z*bfhi(C2.z)+CF.w*bfhi(C3.z)); \
    rr_.us[6] = f2bf(CF.x*bflo(C0.w)+CF.y*bflo(C1.w)+CF.z*bflo(C2.w)+CF.w*bflo(C3.w)); \
    rr_.us[7] = f2bf(CF.x*bfhi(C0.w)+CF.y*bfhi(C1.w)+CF.z*bfhi(C2.w)+CF.w*bfhi(C3.w)); \
    *(uint4*)(DST) = rr_.q; \
  }while(0)

#define DCN_BLEND_Q(C, CF, BUF) do{ \
    ushort* dp_ = &Vs[BUF][vpx*LSTR4 + (vseg<<4)]; \
    DCN_BLEND_H(C[0],C[1],C[2],C[3], CF, dp_); \
    DCN_BLEND_H(C[4],C[5],C[6],C[7], CF, dp_ + 8); \
  }while(0)

#define DCN_COMPUTE_Q2(W, BUF) do{ \
    const ushort* bp_ = &Vs[BUF][(pn0+lo)*LSTR4 + hi*8]; \
    _Pragma("unroll") \
    for(int c_=0;c_<4;c_++){ \
      short8 b0_ = *(const short8*)(bp_ + c_*32); \
      short8 b1_ = *(const short8*)(bp_ + c_*32 + 16*LSTR4); \
      acc[0][0] = __builtin_amdgcn_mfma_f32_16x16x32_bf16(W[4*c_+0], b0_, acc[0][0], 0,0,0); \
      acc[0][1] = __builtin_amdgcn_mfma_f32_16x16x32_bf16(W[4*c_+0], b1_, acc[0][1], 0,0,0); \
      acc[1][0] = __builtin_amdgcn_mfma_f32_16x16x32_bf16(W[4*c_+1], b0_, acc[1][0], 0,0,0); \
      acc[1][1] = __builtin_amdgcn_mfma_f32_16x16x32_bf16(W[4*c_+1], b1_, acc[1][1], 0,0,0); \
      acc[2][0] = __builtin_amdgcn_mfma_f32_16x16x32_bf16(W[4*c_+2], b0_, acc[2][0], 0,0,0); \
      acc[2][1] = __builtin_amdgcn_mfma_f32_16x16x32_bf16(W[4*c_+2], b1_, acc[2][1], 0,0,0); \
      acc[3][0] = __builtin_amdgcn_mfma_f32_16x16x32_bf16(W[4*c_+3], b0_, acc[3][0], 0,0,0); \
      acc[3][1] = __builtin_amdgcn_mfma_f32_16x16x32_bf16(W[4*c_+3], b1_, acc[3][1], 0,0,0); \
    } \
  }while(0)

__global__ __launch_bounds__(512) void k_dcn_mfma(const ushort* __restrict__ xtb,
                        const float* __restrict__ om, const float* __restrict__ b_off,
                        const ushort* __restrict__ Wdb, float* __restrict__ out1){
  __shared__ ushort Vs[2][64*LSTR4];   // 2 x 17408 B
  __shared__ int    sPk[576];
  __shared__ float4 sCf[576];
  int tid = threadIdx.x;
  int px0 = blockIdx.x * 64;
  int b   = blockIdx.y;

  for(int t=tid; t<576; t+=512){
    int k = t>>6, px = t&63;
    int p = px0 + px, hh = p>>6, ww = p&63;
    const float* omp = om + (size_t)b*27*HW + p;
    float dy = omp[(size_t)k*HW]      + b_off[k];
    float dx = omp[(size_t)(9+k)*HW]  + b_off[9+k];
    float mo = sigmoidf_(omp[(size_t)(18+k)*HW] + b_off[18+k]);
    float py  = dy + (float)(hh + k/3 - 1);
    float pxf = dx + (float)(ww + k%3 - 1);
    float y0 = floorf(py), x0 = floorf(pxf);
    float wy = py - y0, wx = pxf - x0;
    float y1 = y0 + 1.0f, x1 = x0 + 1.0f;
    bool vy0 = (y0>=0.f)&&(y0<=63.f), vy1 = (y1>=0.f)&&(y1<=63.f);
    bool vx0 = (x0>=0.f)&&(x0<=63.f), vx1 = (x1>=0.f)&&(x1<=63.f);
    int iy0 = (int)fminf(fmaxf(y0,0.f),63.f);
    int iy1 = (int)fminf(fmaxf(y1,0.f),63.f);
    int ix0 = (int)fminf(fmaxf(x0,0.f),63.f);
    int ix1 = (int)fminf(fmaxf(x1,0.f),63.f);
    sPk[t] = iy0 | (iy1<<6) | (ix0<<12) | (ix1<<18);
    sCf[t] = make_float4((vy0&&vx0)? (1.f-wy)*(1.f-wx)*mo : 0.f,
                         (vy0&&vx1)? (1.f-wy)*wx*mo       : 0.f,
                         (vy1&&vx0)? wy*(1.f-wx)*mo       : 0.f,
                         (vy1&&vx1)? wy*wx*mo             : 0.f);
  }
  __syncthreads();

  int lane = tid&63, wv = tid>>6, lo = lane&15, hi = lane>>4;
  int om0 = (wv>>1)*64, pn0 = (wv&1)*32;
  float4v acc[4][2];
#pragma unroll
  for(int i=0;i<4;i++)
#pragma unroll
    for(int j=0;j<2;j++) acc[i][j] = (float4v){0.f,0.f,0.f,0.f};
  int cbase = (b*HW)<<8;
  int vpx = tid>>3, vseg = tid&7;
  const int wlane = (om0+lo)*32 + hi*8;   // A-frag lane offset within a chunk

  short8 w[16];
  uint4 cE[8], cO[8];
  float4 fE, fO;

  // ---- prologue: gather+blend quad0 -> Vs[0], gather quad1 -> O ----
  DCN_GATHER_Q(0, cE, fE);
  DCN_BLEND_Q(cE, fE, 0);
  DCN_GATHER_Q(1, cO, fO);
  __syncthreads();

#pragma unroll 1
  for(int pb=0; pb<18; pb+=2){
    { // even quad pb: W(pb) FIRST; gather pb+2->E; compute Vs[0]; blend O->Vs[1]
      DCN_WLOAD_ALLQ(pb, w);
      if(pb<16) DCN_GATHER_Q(pb+2, cE, fE);
      DCN_COMPUTE_Q2(w, 0);
      DCN_BLEND_Q(cO, fO, 1);
      __syncthreads();
    }
    { // odd quad pb+1: W(pb+1) FIRST; gather pb+3->O; compute Vs[1]; blend E->Vs[0]
      DCN_WLOAD_ALLQ(pb+1, w);
      if(pb<15) DCN_GATHER_Q(pb+3, cO, fO);
      DCN_COMPUTE_Q2(w, 1);
      if(pb<16) DCN_BLEND_Q(cE, fE, 0);
      __syncthreads();
    }
  }

#pragma unroll
  for(int i=0;i<4;i++){
    int ob = om0 + i*16 + hi*4;
#pragma unroll
    for(int r=0;r<4;r++){
      int o = ob + r;
      float* op = out1 + (size_t)(b*COUT + o)*HW + px0 + pn0 + lo;
#pragma unroll
      for(int j=0;j<2;j++) op[j*16] = acc[i][j][r];
    }
  }
}

// ---------- batchnorm stats (f32 input, for out1) ----------
__global__ void k_bn_stats(const float* __restrict__ xin, float* __restrict__ stats, int per_b){
  int o = blockIdx.x, tid = threadIdx.x;
  float s=0.f, ss=0.f;
  for(int b=0;b<B_;b++){
    const float* p = xin + (size_t)(b*COUT+o)*per_b;
    for(int i=tid;i<per_b;i+=256){ float v = p[i]; s+=v; ss+=v*v; }
  }
  __shared__ float rs[256], rss[256];
  rs[tid]=s; rss[tid]=ss; __syncthreads();
  for(int st=128; st>0; st>>=1){
    if(tid<st){ rs[tid]+=rs[tid+st]; rss[tid]+=rss[tid+st]; }
    __syncthreads();
  }
  if(tid==0){
    float n = (float)(B_*per_b);
    float mean = rs[0]/n;
    float var  = rss[0]/n - mean*mean;
    stats[o*2] = mean; stats[o*2+1] = rsqrtf(var + 1e-5f);
  }
}

// ---------- batchnorm stats over bf16 ct [16 planes][o][4096] ----------
__global__ void k_bn_stats_ct(const ushort* __restrict__ ct, float* __restrict__ stats){
  int o = blockIdx.x, tid = threadIdx.x;
  float s=0.f, ss=0.f;
  for(int pl=0; pl<16; ++pl){
    const ushort* p = ct + (((size_t)(pl*256 + o))<<12);
    for(int i=tid*8; i<4096; i+=2048){
      uint4 v = *(const uint4*)(p + i);
      float f;
      f=bflo(v.x); s+=f; ss+=f*f;  f=bfhi(v.x); s+=f; ss+=f*f;
      f=bflo(v.y); s+=f; ss+=f*f;  f=bfhi(v.y); s+=f; ss+=f*f;
      f=bflo(v.z); s+=f; ss+=f*f;  f=bfhi(v.z); s+=f; ss+=f*f;
      f=bflo(v.w); s+=f; ss+=f*f;  f=bfhi(v.w); s+=f; ss+=f*f;
    }
  }
  __shared__ float rs[256], rss[256];
  rs[tid]=s; rss[tid]=ss; __syncthreads();
  for(int st=128; st>0; st>>=1){
    if(tid<st){ rs[tid]+=rs[tid+st]; rss[tid]+=rss[tid+st]; }
    __syncthreads();
  }
  if(tid==0){
    float n = (float)(16*4096);
    float mean = rs[0]/n;
    float var  = rss[0]/n - mean*mean;
    stats[o*2] = mean; stats[o*2+1] = rsqrtf(var + 1e-5f);
  }
}

// ---------- BN1 apply + relu + transpose -> y1b bf16 [b][p][c] ----------
__global__ void k_bn1_apply_t(const float* __restrict__ out1, const float* __restrict__ stats,
                              const float* __restrict__ gamma, const float* __restrict__ beta,
                              ushort* __restrict__ y1b){
  __shared__ float ts[32][33];
  int tx = threadIdx.x & 31, ty = threadIdx.x >> 5;
  int p0 = blockIdx.x*32, o0 = blockIdx.y*32, b = blockIdx.z;
#pragma unroll
  for(int q=0;q<4;q++){
    int oo = ty + q*8; int o = o0 + oo;
    float m = stats[o*2], rstd = stats[o*2+1];
    float scale = rstd * gamma[o];
    float shift = beta[o] - m * scale;
    float v = out1[(size_t)(b*COUT+o)*HW + p0+tx];
    ts[oo][tx] = fmaxf(v*scale + shift, 0.f);
  }
  __syncthreads();
#pragma unroll
  for(int q=0;q<4;q++){
    int pr = ty + q*8;
    y1b[((size_t)(b*HW + p0+pr)<<8) + o0+tx] = f2bf(ts[tx][pr]);
  }
}

// ---------- conv-transpose MFMA v3: Mb=256 o, Nb=256 px, one (b,pp) ----------
// grid (16,4,4) = 256 blocks, 512 thr = 8 waves (2/SIMD).
// 16 PAIRED phases (BK=64). W JIT from L2 per half-phase. Vs-only dbuf LDS.
__global__ __launch_bounds__(512) void k_convt_mfma(const ushort* __restrict__ y1b,
                        const ushort* __restrict__ WT2c,
                        ushort* __restrict__ ct){
  __shared__ ushort Vs[2][256*LSTR2];   // 2 x 36864 B
  __shared__ int sIdx[1024];
  int tid = threadIdx.x;
  int px0 = blockIdx.x * 256;
  int b   = blockIdx.y;
  int pp  = blockIdx.z;
  int ph = pp>>1, pw = pp&1;

  for(int t=tid; t<1024; t+=512){
    int ab = t>>8, px = t&255;
    int a = ab>>1, bb = ab&1;
    int p = px0+px, r = p>>6, s = p&63;
    int ih = r + ph - 1 + a, iw = s + pw - 1 + bb;
    sIdx[t] = (ih>=0 && ih<64 && iw>=0 && iw<64) ? ((b*HW + ih*64+iw)<<8) : -1;
  }
  __syncthreads();

  int lane = tid&63, wv = tid>>6, lo = lane&15, hi = lane>>4;
  int om0 = (wv>>1)*64;
  int pn0 = (wv&1)*128;
  float4v acc[4][8];
#pragma unroll
  for(int i=0;i<4;i++)
#pragma unroll
    for(int j=0;j<8;j++) acc[i][j] = (float4v){0.f,0.f,0.f,0.f};

  const ushort* wbase = WT2c + ((size_t)pp<<18);
  const int wlaneb = (om0+lo)*32 + hi*8;  // A-frag lane offset within a chunk
  int vpx = tid>>1, vseg = tid&1;         // 2 thr/px, 32 ch each
  uint4 vpre[4];

// pair pc = chunks {2pc,2pc+1}: same ab tap (pc>>2), channels (pc&3)*64..+64.
#define CT3_PREFETCH(PC) do{ \
    int kc0_ = (PC)*2; \
    int ab_ = kc0_>>3, c0_ = (kc0_&7)<<5; \
    int idx_ = sIdx[(ab_<<8) + vpx]; \
    int co_ = c0_ + vseg*32; \
    vpre[0]=make_uint4(0,0,0,0); vpre[1]=make_uint4(0,0,0,0); \
    vpre[2]=make_uint4(0,0,0,0); vpre[3]=make_uint4(0,0,0,0); \
    if(idx_ >= 0){ \
      vpre[0] = *(const uint4*)(y1b + idx_ + co_); \
      vpre[1] = *(const uint4*)(y1b + idx_ + co_ + 8); \
      vpre[2] = *(const uint4*)(y1b + idx_ + co_ + 16); \
      vpre[3] = *(const uint4*)(y1b + idx_ + co_ + 24); \
    } \
  }while(0)

#define CT3_WRITE(BUF) do{ \
    ushort* vp_ = &Vs[BUF][vpx*LSTR2 + vseg*32]; \
    *(uint4*)(vp_)      = vpre[0]; \
    *(uint4*)(vp_ + 8)  = vpre[1]; \
    *(uint4*)(vp_ + 16) = vpre[2]; \
    *(uint4*)(vp_ + 24) = vpre[3]; \
  }while(0)

  // ---- prologue: pair0 -> buf0 ----
  CT3_PREFETCH(0);
  CT3_WRITE(0);
  __syncthreads();

#pragma unroll 1
  for(int pc=0; pc<16; ++pc){
    int cur = pc&1;
    if(pc < 15) CT3_PREFETCH(pc+1);
#pragma unroll
    for(int c=0; c<2; ++c){
      const ushort* wp = wbase + ((size_t)(((pc<<1)|c))<<13) + wlaneb;
      const ushort* bp = &Vs[cur][(pn0+lo)*LSTR2 + c*32 + hi*8];
      short8 bfr[8];
#pragma unroll
      for(int j=0;j<8;j++) bfr[j] = *(const short8*)(bp + j*16*LSTR2);
#pragma unroll
      for(int i=0;i<4;i++){
        short8 afr = *(const short8*)(wp + i*512);
#pragma unroll
        for(int j=0;j<8;j++)
          acc[i][j] = __builtin_amdgcn_mfma_f32_16x16x32_bf16(afr, bfr[j], acc[i][j], 0,0,0);
      }
    }
    if(pc < 15) CT3_WRITE(cur^1);
    __syncthreads();
  }

  ushort* cb = ct + (((size_t)(pp*4 + b)*256)<<12);
#pragma unroll
  for(int i=0;i<4;i++){
#pragma unroll
    for(int r=0;r<4;r++){
      int o = om0 + i*16 + hi*4 + r;
      ushort* row = cb + ((size_t)o<<12) + px0 + pn0 + lo;
#pragma unroll
      for(int j=0;j<8;j++) row[j*16] = f2bf(acc[i][j][r]);
    }
  }
}

// ---------- BN2 apply + relu + parity interleave: ct bf16 -> out f32 ----------
__global__ void k_bn2_apply(const ushort* __restrict__ ct, const float* __restrict__ stats,
                            const float* __restrict__ gamma, const float* __restrict__ beta,
                            float* __restrict__ out){
  int gid = blockIdx.x*256 + threadIdx.x;   // grid 16384
  int e4 = gid<<2;
  int b = e4>>22, o = (e4>>14)&255, q = e4&16383;
  int H2 = q>>7, W2 = q&127;
  int r = H2>>1, ph = H2&1, s0 = W2>>1;
  size_t base0 = (((size_t)((ph*2)*4 + b)*256 + o)<<12) + r*64 + s0;
  unsigned u0 = *(const unsigned*)(ct + base0);
  unsigned u1 = *(const unsigned*)(ct + base0 + ((size_t)4<<20));
  float m = stats[o*2], rstd = stats[o*2+1];
  float sc = rstd * gamma[o];
  float sh = beta[o] - m * sc;
  float4 v;
  v.x = fmaxf(bflo(u0)*sc + sh, 0.f);
  v.y = fmaxf(bflo(u1)*sc + sh, 0.f);
  v.z = fmaxf(bfhi(u0)*sc + sh, 0.f);
  v.w = fmaxf(bfhi(u1)*sc + sh, 0.f);
  *(float4*)(out + e4) = v;
}

extern "C" void kernel_launch(void* const* d_in, const int* in_sizes, int n_in,
                              void* d_out, int out_size, void* d_ws, size_t ws_size,
                              hipStream_t stream){
  (void)in_sizes; (void)n_in; (void)out_size; (void)ws_size;
  const float* x     = (const float*)d_in[0];
  const float* w_off = (const float*)d_in[1];
  const float* b_off = (const float*)d_in[2];
  const float* w_dcn = (const float*)d_in[3];
  const float* gamma1= (const float*)d_in[5];
  const float* beta1 = (const float*)d_in[6];
  const float* w_up  = (const float*)d_in[7];
  const float* gamma2= (const float*)d_in[8];
  const float* beta2 = (const float*)d_in[9];
  float* out = (float*)d_out;

  // Workspace (floats). ct (bf16, 32 MB = 8388608 floats) aliases om+xtb+out1,
  // all of which are dead before k_convt_mfma runs.
  float* ws   = (float*)d_ws;
  ushort* ct  = (ushort*)ws;                       // [0, 8388608) floats
  float* om   = ws;                                // 442368 floats
  ushort* xtb = (ushort*)(ws + 442368);            // 4194304 bf16 = 2097152 floats
  float* out1 = ws + 442368 + 2097152;             // 4194304 floats, ends 6733824 < 8388608
  float* base2 = ws + 8388608;
  ushort* y1b  = (ushort*)base2;                                   // 4194304 bf16
  ushort* WT2c = (ushort*)(base2 + 2097152);                       // 1048576 bf16
  ushort* Wdb  = (ushort*)(base2 + 2097152 + 524288);              // 589824 bf16
  ushort* Wob  = (ushort*)(base2 + 2097152 + 524288 + 294912);     // 73728 bf16
  float* st1   = base2 + 2097152 + 524288 + 294912 + 36864;        // 512
  float* st2   = st1 + 512;                                        // 512

  k_transpose_x <<<dim3(128,8,4), 256, 0, stream>>>(x, xtb);
  k_build_Wob   <<<288,  256, 0, stream>>>(w_off, Wob);
  k_build_Wdb   <<<2304, 256, 0, stream>>>(w_dcn, Wdb);
  k_build_WT2c  <<<4096, 256, 0, stream>>>(w_up, WT2c);
  k_offset_mfma <<<dim3(64,4),  256, 0, stream>>>(xtb, Wob, om);
  k_dcn_mfma    <<<dim3(64,4),  512, 0, stream>>>(xtb, om, b_off, Wdb, out1);
  k_bn_stats    <<<256,  256, 0, stream>>>(out1, st1, 4096);
  k_bn1_apply_t <<<dim3(128,8,4), 256, 0, stream>>>(out1, st1, gamma1, beta1, y1b);
  k_convt_mfma  <<<dim3(16,4,4),  512, 0, stream>>>(y1b, WT2c, ct);
  k_bn_stats_ct <<<256,  256, 0, stream>>>(ct, st2);
  k_bn2_apply   <<<16384,256, 0, stream>>>(ct, st2, gamma2, beta2, out);
}

// Round 9
// 267.799 us; speedup vs baseline: 1.0711x; 1.0260x over previous
//
#include <hip/hip_runtime.h>
#include <hip/hip_bf16.h>
#include <math.h>

// Problem constants
#define B_   4
#define CIN  256
#define COUT 256
#define HW   4096   // 64*64

typedef __attribute__((ext_vector_type(8))) short short8;
typedef __attribute__((ext_vector_type(4))) float float4v;

// LDS row strides (ushorts).
// LSTR2 (64-ch rows): 144 B = 36 dwords (36 mod 32 = 4 -> proven 2-way pattern).
// LSTR4 (128-ch rows): 272 B = 68 dwords (68 mod 32 = 4 -> same pattern).
#define LSTR  40
#define LSTR2 72
#define LSTR4 136

__device__ __forceinline__ float sigmoidf_(float v){ return 1.0f/(1.0f+expf(-v)); }
__device__ __forceinline__ ushort f2bf(float f){
  union { float f; unsigned u; } x; x.f = f;
  unsigned r = x.u + 0x7fffu + ((x.u>>16)&1u);
  return (ushort)(r>>16);
}
__device__ __forceinline__ float bflo(unsigned u){ union{unsigned u; float f;} c; c.u = u<<16;          return c.f; }
__device__ __forceinline__ float bfhi(unsigned u){ union{unsigned u; float f;} c; c.u = u & 0xffff0000u; return c.f; }

// ---------- transpose x [B][C][HW] -> xtb [B][HW][C] bf16 ----------
__global__ void k_transpose_x(const float* __restrict__ x, ushort* __restrict__ xtb){
  __shared__ float ts[32][33];
  int tx = threadIdx.x & 31, ty = threadIdx.x >> 5;
  int p0 = blockIdx.x * 32, c0 = blockIdx.y * 32, b = blockIdx.z;
  const float* xb = x + (size_t)b*CIN*HW;
#pragma unroll
  for(int q=0;q<4;q++){
    int c = ty + q*8;
    ts[c][tx] = xb[(size_t)(c0+c)*HW + p0+tx];
  }
  __syncthreads();
#pragma unroll
  for(int q=0;q<4;q++){
    int pr = ty + q*8;
    xtb[((size_t)(b*HW + p0+pr)<<8) + c0+tx] = f2bf(ts[tx][pr]);
  }
}

// ---------- fused weight re-layouts (bf16, K-chunked [kc][o][kk]) ----------
// grid 288 + 2304 + 4096 = 6688 blocks; switch on blockIdx.x range.
__global__ void k_build_all(const float* __restrict__ w_off, const float* __restrict__ w_dcn,
                            const float* __restrict__ w_up,
                            ushort* __restrict__ Wob, ushort* __restrict__ Wdb,
                            ushort* __restrict__ WT2c){
  int bid = blockIdx.x;
  if(bid < 288){
    int f = bid*256 + threadIdx.x;
    int kc = f>>10, o = (f>>5)&31, kk = f&31;
    int k = kc*32 + kk, tap = k>>8, c = k&255;
    float v = (o < 27) ? w_off[(size_t)o*2304 + c*9 + tap] : 0.f;
    Wob[f] = f2bf(v);
  } else if(bid < 288+2304){
    int f = (bid-288)*256 + threadIdx.x;
    int kc = f>>13, o = (f>>5)&255, kk = f&31;
    int k = kc>>3, c = ((kc&7)<<5) | kk;
    Wdb[f] = f2bf(w_dcn[(size_t)o*2304 + c*9 + k]);
  } else {
    int f = (bid-2592)*256 + threadIdx.x;
    int pp = f>>18, kc = (f>>13)&31, o = (f>>5)&255, kk = f&31;
    int k = kc*32 + kk, ab = k>>8, c = k&255;
    int a = ab>>1, bb = ab&1, ph = pp>>1, pw = pp&1;
    WT2c[f] = f2bf(w_up[(size_t)(c*COUT+o)*16 + (3-ph-2*a)*4 + (3-pw-2*bb)]);
  }
}

// ---------- offset conv MFMA: M=32(27), Nb=64 px, K=2304, QUAD chunks (BK=128) ----------
// 18 quad-phases. XCD-b affinity remap: fb%8 -> XCD (dispatch round-robin);
// b = (fb&7)>>1 so each XCD serves ONE b-slice of xtb (2 MB <= 4 MB XCD-L2).
__global__ __launch_bounds__(256) void k_offset_mfma(const ushort* __restrict__ xtb,
                        const ushort* __restrict__ Wob, float* __restrict__ om){
  __shared__ ushort Vs[2][64*LSTR4];   // 2 x 17408 B
  __shared__ int sIdx[576];
  int tid = threadIdx.x;
  int fb  = blockIdx.x + (blockIdx.y<<6);      // 0..255
  int b   = (fb&7)>>1;
  int px0 = ((((fb>>3)<<1) | (fb&1))) << 6;    // x = 2*(fb>>3) + (fb&1)
  for(int t=tid; t<576; t+=256){
    int tap = t>>6, px = t&63;
    int p = px0+px, hh = p>>6, ww = p&63;
    int ih = hh + tap/3 - 1, iw = ww + tap%3 - 1;
    sIdx[t] = (ih>=0 && ih<64 && iw>=0 && iw<64) ? ((b*HW + ih*64+iw)<<8) : -1;
  }
  __syncthreads();

  int lane = tid&63, wv = tid>>6, lo = lane&15, hi = lane>>4;
  float4v acc[2];
  acc[0] = acc[1] = (float4v){0.f,0.f,0.f,0.f};
  int vpx = tid>>2, vseg = tid&3;
  const int wlane = lo*32 + hi*8;   // A-frag lane offset within a chunk

// issue all 8 W fragments for quad Q (4 chunks x 2 m-tiles)
#define OFF_WLOAD_ALLQ(Q, W) do{ \
    _Pragma("unroll") \
    for(int c_=0;c_<4;c_++){ \
      const ushort* wp_ = Wob + (((Q)*4+c_)<<10) + wlane; \
      W[2*c_+0] = *(const short8*)(wp_); \
      W[2*c_+1] = *(const short8*)(wp_ + 512); \
    } \
  }while(0)

// quad gather: 32 ch/thread (4x uint4), 4 thr/px cover 128 ch
#define OFF_GATHER_Q(Q, V) do{ \
    int k_ = (Q)>>1, c0_ = ((Q)&1)<<7; \
    int idx_ = sIdx[(k_<<6)+vpx]; \
    int coff_ = c0_ + (vseg<<5); \
    V[0]=make_uint4(0,0,0,0); V[1]=make_uint4(0,0,0,0); \
    V[2]=make_uint4(0,0,0,0); V[3]=make_uint4(0,0,0,0); \
    if(idx_ >= 0){ \
      V[0] = *(const uint4*)(xtb + idx_ + coff_); \
      V[1] = *(const uint4*)(xtb + idx_ + coff_ + 8); \
      V[2] = *(const uint4*)(xtb + idx_ + coff_ + 16); \
      V[3] = *(const uint4*)(xtb + idx_ + coff_ + 24); \
    } \
  }while(0)

#define OFF_VWRITE_Q(V, BUF) do{ \
    ushort* vp_ = &Vs[BUF][vpx*LSTR4 + (vseg<<5)]; \
    *(uint4*)(vp_)      = V[0]; \
    *(uint4*)(vp_ + 8)  = V[1]; \
    *(uint4*)(vp_ + 16) = V[2]; \
    *(uint4*)(vp_ + 24) = V[3]; \
  }while(0)

#define OFF_COMPUTE_Q2(W, BUF) do{ \
    const ushort* bp_ = &Vs[BUF][(wv*16+lo)*LSTR4 + hi*8]; \
    _Pragma("unroll") \
    for(int c_=0;c_<4;c_++){ \
      short8 ba_ = *(const short8*)(bp_ + c_*32); \
      acc[0] = __builtin_amdgcn_mfma_f32_16x16x32_bf16(W[2*c_+0], ba_, acc[0], 0,0,0); \
      acc[1] = __builtin_amdgcn_mfma_f32_16x16x32_bf16(W[2*c_+1], ba_, acc[1], 0,0,0); \
    } \
  }while(0)

  short8 w[8];
  uint4 vE[4], vO[4];
  // ---- prologue: V quad0 -> Vs[0], V quad1 -> regs ----
  OFF_GATHER_Q(0, vE);
  OFF_VWRITE_Q(vE, 0);
  OFF_GATHER_Q(1, vO);
  __syncthreads();

#pragma unroll 1
  for(int pb=0; pb<18; pb+=2){
    { // even quad pb: W(pb) first; gather pb+2->E; compute Vs[0]; write O->Vs[1]
      OFF_WLOAD_ALLQ(pb, w);
      if(pb<16) OFF_GATHER_Q(pb+2, vE);
      OFF_COMPUTE_Q2(w, 0);
      OFF_VWRITE_Q(vO, 1);
      __syncthreads();
    }
    { // odd quad pb+1: W(pb+1) first; gather pb+3->O; compute Vs[1]; write E->Vs[0]
      OFF_WLOAD_ALLQ(pb+1, w);
      if(pb<15) OFF_GATHER_Q(pb+3, vO);
      OFF_COMPUTE_Q2(w, 1);
      if(pb<16) OFF_VWRITE_Q(vE, 0);
      __syncthreads();
    }
  }
  int p = px0 + wv*16 + lo;
#pragma unroll
  for(int mi=0;mi<2;mi++){
    int ob = mi*16 + hi*4;
    float4v a = (mi==0) ? acc[0] : acc[1];
#pragma unroll
    for(int r=0;r<4;r++){
      int o = ob + r;
      if(o < 27) om[(size_t)(b*27+o)*HW + p] = a[r];
    }
  }
}

// ---------- DCN MFMA: Mb=256, Nb=64, K=2304, QUAD chunks (BK=128) ----------
// 18 quad-phases. grid (64,4), 512 thr = 8 waves (2/SIMD).
// XCD-b affinity remap (see k_offset). W-first issue order per phase.
// b_dcn dropped: BN1 subtracts the per-channel mean, so a uniform bias cancels.
#define DCN_WLOAD_ALLQ(Q, W) do{ \
    _Pragma("unroll") \
    for(int c_=0;c_<4;c_++){ \
      const ushort* wp_ = Wdb + ((size_t)((Q)*4+c_)<<13) + wlane; \
      W[4*c_+0] = *(const short8*)(wp_); \
      W[4*c_+1] = *(const short8*)(wp_ + 512); \
      W[4*c_+2] = *(const short8*)(wp_ + 1024); \
      W[4*c_+3] = *(const short8*)(wp_ + 1536); \
    } \
  }while(0)

#define DCN_GATHER_Q(Q, C, CF) do{ \
    int k_ = (Q)>>1, c0_ = ((Q)&1)<<7; \
    int t_ = (k_<<6) + vpx; \
    int pk_ = sPk[t_]; CF = sCf[t_]; \
    int coff_ = c0_ + (vseg<<4); \
    int iy0_=pk_&63, iy1_=(pk_>>6)&63, ix0_=(pk_>>12)&63, ix1_=(pk_>>18)&63; \
    const ushort* p00_ = xtb + cbase + (((iy0_<<6)+ix0_)<<8) + coff_; \
    const ushort* p01_ = xtb + cbase + (((iy0_<<6)+ix1_)<<8) + coff_; \
    const ushort* p10_ = xtb + cbase + (((iy1_<<6)+ix0_)<<8) + coff_; \
    const ushort* p11_ = xtb + cbase + (((iy1_<<6)+ix1_)<<8) + coff_; \
    C[0] = *(const uint4*)(p00_);     C[4] = *(const uint4*)(p00_ + 8); \
    C[1] = *(const uint4*)(p01_);     C[5] = *(const uint4*)(p01_ + 8); \
    C[2] = *(const uint4*)(p10_);     C[6] = *(const uint4*)(p10_ + 8); \
    C[3] = *(const uint4*)(p11_);     C[7] = *(const uint4*)(p11_ + 8); \
  }while(0)

#define DCN_BLEND_H(C0,C1,C2,C3, CF, DST) do{ \
    union{ ushort us[8]; uint4 q; } rr_; \
    rr_.us[0] = f2bf(CF.x*bflo(C0.x)+CF.y*bflo(C1.x)+CF.z*bflo(C2.x)+CF.w*bflo(C3.x)); \
    rr_.us[1] = f2bf(CF.x*bfhi(C0.x)+CF.y*bfhi(C1.x)+CF.z*bfhi(C2.x)+CF.w*bfhi(C3.x)); \
    rr_.us[2] = f2bf(CF.x*bflo(C0.y)+CF.y*bflo(C1.y)+CF.z*bflo(C2.y)+CF.w*bflo(C3.y)); \
    rr_.us[3] = f2bf(CF.x*bfhi(C0.y)+CF.y*bfhi(C1.y)+CF.z*bfhi(C2.y)+CF.w*bfhi(C3.y)); \
    rr_.us[4] = f2bf(CF.x*bflo(C0.z)+CF.y*bflo(C1.z)+CF.z*bflo(C2.z)+CF.w*bflo(C3.z)); \
    rr_.us[5] = f2bf(CF.x*bfhi(C0.z)+CF.y*bfhi(C1.z)+CF.z*bfhi(C2.z)+CF.w*bfhi(C3.z)); \
    rr_.us[6] = f2bf(CF.x*bflo(C0.w)+CF.y*bflo(C1.w)+CF.z*bflo(C2.w)+CF.w*bflo(C3.w)); \
    rr_.us[7] = f2bf(CF.x*bfhi(C0.w)+CF.y*bfhi(C1.w)+CF.z*bfhi(C2.w)+CF.w*bfhi(C3.w)); \
    *(uint4*)(DST) = rr_.q; \
  }while(0)

#define DCN_BLEND_Q(C, CF, BUF) do{ \
    ushort* dp_ = &Vs[BUF][vpx*LSTR4 + (vseg<<4)]; \
    DCN_BLEND_H(C[0],C[1],C[2],C[3], CF, dp_); \
    DCN_BLEND_H(C[4],C[5],C[6],C[7], CF, dp_ + 8); \
  }while(0)

#define DCN_COMPUTE_Q2(W, BUF) do{ \
    const ushort* bp_ = &Vs[BUF][(pn0+lo)*LSTR4 + hi*8]; \
    _Pragma("unroll") \
    for(int c_=0;c_<4;c_++){ \
      short8 b0_ = *(const short8*)(bp_ + c_*32); \
      short8 b1_ = *(const short8*)(bp_ + c_*32 + 16*LSTR4); \
      acc[0][0] = __builtin_amdgcn_mfma_f32_16x16x32_bf16(W[4*c_+0], b0_, acc[0][0], 0,0,0); \
      acc[0][1] = __builtin_amdgcn_mfma_f32_16x16x32_bf16(W[4*c_+0], b1_, acc[0][1], 0,0,0); \
      acc[1][0] = __builtin_amdgcn_mfma_f32_16x16x32_bf16(W[4*c_+1], b0_, acc[1][0], 0,0,0); \
      acc[1][1] = __builtin_amdgcn_mfma_f32_16x16x32_bf16(W[4*c_+1], b1_, acc[1][1], 0,0,0); \
      acc[2][0] = __builtin_amdgcn_mfma_f32_16x16x32_bf16(W[4*c_+2], b0_, acc[2][0], 0,0,0); \
      acc[2][1] = __builtin_amdgcn_mfma_f32_16x16x32_bf16(W[4*c_+2], b1_, acc[2][1], 0,0,0); \
      acc[3][0] = __builtin_amdgcn_mfma_f32_16x16x32_bf16(W[4*c_+3], b0_, acc[3][0], 0,0,0); \
      acc[3][1] = __builtin_amdgcn_mfma_f32_16x16x32_bf16(W[4*c_+3], b1_, acc[3][1], 0,0,0); \
    } \
  }while(0)

__global__ __launch_bounds__(512) void k_dcn_mfma(const ushort* __restrict__ xtb,
                        const float* __restrict__ om, const float* __restrict__ b_off,
                        const ushort* __restrict__ Wdb, float* __restrict__ out1){
  __shared__ ushort Vs[2][64*LSTR4];   // 2 x 17408 B
  __shared__ int    sPk[576];
  __shared__ float4 sCf[576];
  int tid = threadIdx.x;
  int fb  = blockIdx.x + (blockIdx.y<<6);      // 0..255
  int b   = (fb&7)>>1;
  int px0 = ((((fb>>3)<<1) | (fb&1))) << 6;

  for(int t=tid; t<576; t+=512){
    int k = t>>6, px = t&63;
    int p = px0 + px, hh = p>>6, ww = p&63;
    const float* omp = om + (size_t)b*27*HW + p;
    float dy = omp[(size_t)k*HW]      + b_off[k];
    float dx = omp[(size_t)(9+k)*HW]  + b_off[9+k];
    float mo = sigmoidf_(omp[(size_t)(18+k)*HW] + b_off[18+k]);
    float py  = dy + (float)(hh + k/3 - 1);
    float pxf = dx + (float)(ww + k%3 - 1);
    float y0 = floorf(py), x0 = floorf(pxf);
    float wy = py - y0, wx = pxf - x0;
    float y1 = y0 + 1.0f, x1 = x0 + 1.0f;
    bool vy0 = (y0>=0.f)&&(y0<=63.f), vy1 = (y1>=0.f)&&(y1<=63.f);
    bool vx0 = (x0>=0.f)&&(x0<=63.f), vx1 = (x1>=0.f)&&(x1<=63.f);
    int iy0 = (int)fminf(fmaxf(y0,0.f),63.f);
    int iy1 = (int)fminf(fmaxf(y1,0.f),63.f);
    int ix0 = (int)fminf(fmaxf(x0,0.f),63.f);
    int ix1 = (int)fminf(fmaxf(x1,0.f),63.f);
    sPk[t] = iy0 | (iy1<<6) | (ix0<<12) | (ix1<<18);
    sCf[t] = make_float4((vy0&&vx0)? (1.f-wy)*(1.f-wx)*mo : 0.f,
                         (vy0&&vx1)? (1.f-wy)*wx*mo       : 0.f,
                         (vy1&&vx0)? wy*(1.f-wx)*mo       : 0.f,
                         (vy1&&vx1)? wy*wx*mo             : 0.f);
  }
  __syncthreads();

  int lane = tid&63, wv = tid>>6, lo = lane&15, hi = lane>>4;
  int om0 = (wv>>1)*64, pn0 = (wv&1)*32;
  float4v acc[4][2];
#pragma unroll
  for(int i=0;i<4;i++)
#pragma unroll
    for(int j=0;j<2;j++) acc[i][j] = (float4v){0.f,0.f,0.f,0.f};
  int cbase = (b*HW)<<8;
  int vpx = tid>>3, vseg = tid&7;
  const int wlane = (om0+lo)*32 + hi*8;   // A-frag lane offset within a chunk

  short8 w[16];
  uint4 cE[8], cO[8];
  float4 fE, fO;

  // ---- prologue: gather+blend quad0 -> Vs[0], gather quad1 -> O ----
  DCN_GATHER_Q(0, cE, fE);
  DCN_BLEND_Q(cE, fE, 0);
  DCN_GATHER_Q(1, cO, fO);
  __syncthreads();

#pragma unroll 1
  for(int pb=0; pb<18; pb+=2){
    { // even quad pb: W(pb) FIRST; gather pb+2->E; compute Vs[0]; blend O->Vs[1]
      DCN_WLOAD_ALLQ(pb, w);
      if(pb<16) DCN_GATHER_Q(pb+2, cE, fE);
      DCN_COMPUTE_Q2(w, 0);
      DCN_BLEND_Q(cO, fO, 1);
      __syncthreads();
    }
    { // odd quad pb+1: W(pb+1) FIRST; gather pb+3->O; compute Vs[1]; blend E->Vs[0]
      DCN_WLOAD_ALLQ(pb+1, w);
      if(pb<15) DCN_GATHER_Q(pb+3, cO, fO);
      DCN_COMPUTE_Q2(w, 1);
      if(pb<16) DCN_BLEND_Q(cE, fE, 0);
      __syncthreads();
    }
  }

#pragma unroll
  for(int i=0;i<4;i++){
    int ob = om0 + i*16 + hi*4;
#pragma unroll
    for(int r=0;r<4;r++){
      int o = ob + r;
      float* op = out1 + (size_t)(b*COUT + o)*HW + px0 + pn0 + lo;
#pragma unroll
      for(int j=0;j<2;j++) op[j*16] = acc[i][j][r];
    }
  }
}

// ---------- batchnorm stats (f32 input, for out1) ----------
__global__ void k_bn_stats(const float* __restrict__ xin, float* __restrict__ stats, int per_b){
  int o = blockIdx.x, tid = threadIdx.x;
  float s=0.f, ss=0.f;
  for(int b=0;b<B_;b++){
    const float* p = xin + (size_t)(b*COUT+o)*per_b;
    for(int i=tid;i<per_b;i+=256){ float v = p[i]; s+=v; ss+=v*v; }
  }
  __shared__ float rs[256], rss[256];
  rs[tid]=s; rss[tid]=ss; __syncthreads();
  for(int st=128; st>0; st>>=1){
    if(tid<st){ rs[tid]+=rs[tid+st]; rss[tid]+=rss[tid+st]; }
    __syncthreads();
  }
  if(tid==0){
    float n = (float)(B_*per_b);
    float mean = rs[0]/n;
    float var  = rss[0]/n - mean*mean;
    stats[o*2] = mean; stats[o*2+1] = rsqrtf(var + 1e-5f);
  }
}

// ---------- batchnorm stats over bf16 ct [16 planes][o][4096] ----------
__global__ void k_bn_stats_ct(const ushort* __restrict__ ct, float* __restrict__ stats){
  int o = blockIdx.x, tid = threadIdx.x;
  float s=0.f, ss=0.f;
  for(int pl=0; pl<16; ++pl){
    const ushort* p = ct + (((size_t)(pl*256 + o))<<12);
    for(int i=tid*8; i<4096; i+=2048){
      uint4 v = *(const uint4*)(p + i);
      float f;
      f=bflo(v.x); s+=f; ss+=f*f;  f=bfhi(v.x); s+=f; ss+=f*f;
      f=bflo(v.y); s+=f; ss+=f*f;  f=bfhi(v.y); s+=f; ss+=f*f;
      f=bflo(v.z); s+=f; ss+=f*f;  f=bfhi(v.z); s+=f; ss+=f*f;
      f=bflo(v.w); s+=f; ss+=f*f;  f=bfhi(v.w); s+=f; ss+=f*f;
    }
  }
  __shared__ float rs[256], rss[256];
  rs[tid]=s; rss[tid]=ss; __syncthreads();
  for(int st=128; st>0; st>>=1){
    if(tid<st){ rs[tid]+=rs[tid+st]; rss[tid]+=rss[tid+st]; }
    __syncthreads();
  }
  if(tid==0){
    float n = (float)(16*4096);
    float mean = rs[0]/n;
    float var  = rss[0]/n - mean*mean;
    stats[o*2] = mean; stats[o*2+1] = rsqrtf(var + 1e-5f);
  }
}

// ---------- BN1 apply + relu + transpose -> y1b bf16 [b][p][c] ----------
__global__ void k_bn1_apply_t(const float* __restrict__ out1, const float* __restrict__ stats,
                              const float* __restrict__ gamma, const float* __restrict__ beta,
                              ushort* __restrict__ y1b){
  __shared__ float ts[32][33];
  int tx = threadIdx.x & 31, ty = threadIdx.x >> 5;
  int p0 = blockIdx.x*32, o0 = blockIdx.y*32, b = blockIdx.z;
#pragma unroll
  for(int q=0;q<4;q++){
    int oo = ty + q*8; int o = o0 + oo;
    float m = stats[o*2], rstd = stats[o*2+1];
    float scale = rstd * gamma[o];
    float shift = beta[o] - m * scale;
    float v = out1[(size_t)(b*COUT+o)*HW + p0+tx];
    ts[oo][tx] = fmaxf(v*scale + shift, 0.f);
  }
  __syncthreads();
#pragma unroll
  for(int q=0;q<4;q++){
    int pr = ty + q*8;
    y1b[((size_t)(b*HW + p0+pr)<<8) + o0+tx] = f2bf(ts[tx][pr]);
  }
}

// ---------- conv-transpose MFMA v3: Mb=256 o, Nb=256 px, one (b,pp) ----------
// grid (16,4,4) = 256 blocks, 512 thr = 8 waves (2/SIMD).
// XCD-b affinity remap: each XCD serves one b-slice of y1b (2 MB) + 2 pp-slices
// of WT2c (1 MB) -> 3 MB working set <= 4 MB XCD-L2.
__global__ __launch_bounds__(512) void k_convt_mfma(const ushort* __restrict__ y1b,
                        const ushort* __restrict__ WT2c,
                        ushort* __restrict__ ct){
  __shared__ ushort Vs[2][256*LSTR2];   // 2 x 36864 B
  __shared__ int sIdx[1024];
  int tid = threadIdx.x;
  int fb  = blockIdx.x + (blockIdx.y<<4) + (blockIdx.z<<6);  // 0..255
  int jj = fb&7, rr2 = fb>>3;
  int b   = jj>>1;
  int pp  = ((rr2>>4)<<1) | (jj&1);
  int px0 = (rr2&15) << 8;
  int ph = pp>>1, pw = pp&1;

  for(int t=tid; t<1024; t+=512){
    int ab = t>>8, px = t&255;
    int a = ab>>1, bb = ab&1;
    int p = px0+px, r = p>>6, s = p&63;
    int ih = r + ph - 1 + a, iw = s + pw - 1 + bb;
    sIdx[t] = (ih>=0 && ih<64 && iw>=0 && iw<64) ? ((b*HW + ih*64+iw)<<8) : -1;
  }
  __syncthreads();

  int lane = tid&63, wv = tid>>6, lo = lane&15, hi = lane>>4;
  int om0 = (wv>>1)*64;
  int pn0 = (wv&1)*128;
  float4v acc[4][8];
#pragma unroll
  for(int i=0;i<4;i++)
#pragma unroll
    for(int j=0;j<8;j++) acc[i][j] = (float4v){0.f,0.f,0.f,0.f};

  const ushort* wbase = WT2c + ((size_t)pp<<18);
  const int wlaneb = (om0+lo)*32 + hi*8;  // A-frag lane offset within a chunk
  int vpx = tid>>1, vseg = tid&1;         // 2 thr/px, 32 ch each
  uint4 vpre[4];

// pair pc = chunks {2pc,2pc+1}: same ab tap (pc>>2), channels (pc&3)*64..+64.
#define CT3_PREFETCH(PC) do{ \
    int kc0_ = (PC)*2; \
    int ab_ = kc0_>>3, c0_ = (kc0_&7)<<5; \
    int idx_ = sIdx[(ab_<<8) + vpx]; \
    int co_ = c0_ + vseg*32; \
    vpre[0]=make_uint4(0,0,0,0); vpre[1]=make_uint4(0,0,0,0); \
    vpre[2]=make_uint4(0,0,0,0); vpre[3]=make_uint4(0,0,0,0); \
    if(idx_ >= 0){ \
      vpre[0] = *(const uint4*)(y1b + idx_ + co_); \
      vpre[1] = *(const uint4*)(y1b + idx_ + co_ + 8); \
      vpre[2] = *(const uint4*)(y1b + idx_ + co_ + 16); \
      vpre[3] = *(const uint4*)(y1b + idx_ + co_ + 24); \
    } \
  }while(0)

#define CT3_WRITE(BUF) do{ \
    ushort* vp_ = &Vs[BUF][vpx*LSTR2 + vseg*32]; \
    *(uint4*)(vp_)      = vpre[0]; \
    *(uint4*)(vp_ + 8)  = vpre[1]; \
    *(uint4*)(vp_ + 16) = vpre[2]; \
    *(uint4*)(vp_ + 24) = vpre[3]; \
  }while(0)

  // ---- prologue: pair0 -> buf0 ----
  CT3_PREFETCH(0);
  CT3_WRITE(0);
  __syncthreads();

#pragma unroll 1
  for(int pc=0; pc<16; ++pc){
    int cur = pc&1;
    if(pc < 15) CT3_PREFETCH(pc+1);
#pragma unroll
    for(int c=0; c<2; ++c){
      const ushort* wp = wbase + ((size_t)(((pc<<1)|c))<<13) + wlaneb;
      const ushort* bp = &Vs[cur][(pn0+lo)*LSTR2 + c*32 + hi*8];
      short8 bfr[8];
#pragma unroll
      for(int j=0;j<8;j++) bfr[j] = *(const short8*)(bp + j*16*LSTR2);
#pragma unroll
      for(int i=0;i<4;i++){
        short8 afr = *(const short8*)(wp + i*512);
#pragma unroll
        for(int j=0;j<8;j++)
          acc[i][j] = __builtin_amdgcn_mfma_f32_16x16x32_bf16(afr, bfr[j], acc[i][j], 0,0,0);
      }
    }
    if(pc < 15) CT3_WRITE(cur^1);
    __syncthreads();
  }

  ushort* cb = ct + (((size_t)(pp*4 + b)*256)<<12);
#pragma unroll
  for(int i=0;i<4;i++){
#pragma unroll
    for(int r=0;r<4;r++){
      int o = om0 + i*16 + hi*4 + r;
      ushort* row = cb + ((size_t)o<<12) + px0 + pn0 + lo;
#pragma unroll
      for(int j=0;j<8;j++) row[j*16] = f2bf(acc[i][j][r]);
    }
  }
}

// ---------- BN2 apply + relu + parity interleave: ct bf16 -> out f32 ----------
__global__ void k_bn2_apply(const ushort* __restrict__ ct, const float* __restrict__ stats,
                            const float* __restrict__ gamma, const float* __restrict__ beta,
                            float* __restrict__ out){
  int gid = blockIdx.x*256 + threadIdx.x;   // grid 16384
  int e4 = gid<<2;
  int b = e4>>22, o = (e4>>14)&255, q = e4&16383;
  int H2 = q>>7, W2 = q&127;
  int r = H2>>1, ph = H2&1, s0 = W2>>1;
  size_t base0 = (((size_t)((ph*2)*4 + b)*256 + o)<<12) + r*64 + s0;
  unsigned u0 = *(const unsigned*)(ct + base0);
  unsigned u1 = *(const unsigned*)(ct + base0 + ((size_t)4<<20));
  float m = stats[o*2], rstd = stats[o*2+1];
  float sc = rstd * gamma[o];
  float sh = beta[o] - m * sc;
  float4 v;
  v.x = fmaxf(bflo(u0)*sc + sh, 0.f);
  v.y = fmaxf(bflo(u1)*sc + sh, 0.f);
  v.z = fmaxf(bfhi(u0)*sc + sh, 0.f);
  v.w = fmaxf(bfhi(u1)*sc + sh, 0.f);
  *(float4*)(out + e4) = v;
}

extern "C" void kernel_launch(void* const* d_in, const int* in_sizes, int n_in,
                              void* d_out, int out_size, void* d_ws, size_t ws_size,
                              hipStream_t stream){
  (void)in_sizes; (void)n_in; (void)out_size; (void)ws_size;
  const float* x     = (const float*)d_in[0];
  const float* w_off = (const float*)d_in[1];
  const float* b_off = (const float*)d_in[2];
  const float* w_dcn = (const float*)d_in[3];
  const float* gamma1= (const float*)d_in[5];
  const float* beta1 = (const float*)d_in[6];
  const float* w_up  = (const float*)d_in[7];
  const float* gamma2= (const float*)d_in[8];
  const float* beta2 = (const float*)d_in[9];
  float* out = (float*)d_out;

  // Workspace (floats). ct (bf16, 32 MB = 8388608 floats) aliases om+xtb+out1,
  // all of which are dead before k_convt_mfma runs.
  float* ws   = (float*)d_ws;
  ushort* ct  = (ushort*)ws;                       // [0, 8388608) floats
  float* om   = ws;                                // 442368 floats
  ushort* xtb = (ushort*)(ws + 442368);            // 4194304 bf16 = 2097152 floats
  float* out1 = ws + 442368 + 2097152;             // 4194304 floats, ends 6733824 < 8388608
  float* base2 = ws + 8388608;
  ushort* y1b  = (ushort*)base2;                                   // 4194304 bf16
  ushort* WT2c = (ushort*)(base2 + 2097152);                       // 1048576 bf16
  ushort* Wdb  = (ushort*)(base2 + 2097152 + 524288);              // 589824 bf16
  ushort* Wob  = (ushort*)(base2 + 2097152 + 524288 + 294912);     // 73728 bf16
  float* st1   = base2 + 2097152 + 524288 + 294912 + 36864;        // 512
  float* st2   = st1 + 512;                                        // 512

  k_transpose_x <<<dim3(128,8,4), 256, 0, stream>>>(x, xtb);
  k_build_all   <<<6688, 256, 0, stream>>>(w_off, w_dcn, w_up, Wob, Wdb, WT2c);
  k_offset_mfma <<<dim3(64,4),  256, 0, stream>>>(xtb, Wob, om);
  k_dcn_mfma    <<<dim3(64,4),  512, 0, stream>>>(xtb, om, b_off, Wdb, out1);
  k_bn_stats    <<<256,  256, 0, stream>>>(out1, st1, 4096);
  k_bn1_apply_t <<<dim3(128,8,4), 256, 0, stream>>>(out1, st1, gamma1, beta1, y1b);
  k_convt_mfma  <<<dim3(16,4,4),  512, 0, stream>>>(y1b, WT2c, ct);
  k_bn_stats_ct <<<256,  256, 0, stream>>>(ct, st2);
  k_bn2_apply   <<<16384,256, 0, stream>>>(ct, st2, gamma2, beta2, out);
}